// Round 10
// baseline (153.237 us; speedup 1.0000x reference)
//
#include <hip/hip_runtime.h>
#include <hip/hip_bf16.h>

// NTM cell on MI355X. B=2048, IN=64, CTRL=512, M=1024, V=64, OUT=64.
// 4 dispatches. This round: k_pre GEMM BK 128->256 (4 serial rounds instead
// of 8; halves barrier count and per-round global-load latency exposure;
// identical MFMA count/order -> bitwise-identical result) + LDS right-sized
// to 16x264 + 64x264 = 42KB (As was declared 64-row, only 16 used).
// k_gates keeps the r9 3-deep vmcnt(12) pipeline; k_heads/k_tail unchanged.

typedef unsigned short u16;
typedef __attribute__((ext_vector_type(8))) short bf16x8;
typedef __attribute__((ext_vector_type(4))) float f32x4;

#define MFMA_BF16(a, b, c) __builtin_amdgcn_mfma_f32_16x16x32_bf16((a), (b), (c), 0, 0, 0)
#define LDW 136
#define LDW2 264
#define SLDW 520

__device__ __forceinline__ void dma16(const void* g, void* l) {
    __builtin_amdgcn_global_load_lds(
        (const __attribute__((address_space(1))) unsigned int*)g,
        (__attribute__((address_space(3))) unsigned int*)l, 16, 0, 0);
}

__device__ __forceinline__ u16 f2bf(float f) {
    union { float f; unsigned int u; } a; a.f = f;
    return (u16)((a.u + 0x7FFFu + ((a.u >> 16) & 1u)) >> 16);
}

__device__ __forceinline__ void pack_store4(float a0, float a1, float a2, float a3, u16* d) {
    union { __hip_bfloat162 h[2]; uint2 u; } cv;
    cv.h[0] = __float22bfloat162_rn(make_float2(a0, a1));
    cv.h[1] = __float22bfloat162_rn(make_float2(a2, a3));
    *(uint2*)d = cv.u;
}

__device__ __forceinline__ void cvt4(const float* __restrict__ s, u16* __restrict__ d) {
    float4 v = *(const float4*)s;
    pack_store4(v.x, v.y, v.z, v.w, d);
}

__device__ __forceinline__ uint4 cvt8u(const float* __restrict__ s) {
    float4 v0 = *(const float4*)(s);
    float4 v1 = *(const float4*)(s + 4);
    union { __hip_bfloat162 h[4]; uint4 u; } r;
    r.h[0] = __float22bfloat162_rn(make_float2(v0.x, v0.y));
    r.h[1] = __float22bfloat162_rn(make_float2(v0.z, v0.w));
    r.h[2] = __float22bfloat162_rn(make_float2(v1.x, v1.y));
    r.h[3] = __float22bfloat162_rn(make_float2(v1.z, v1.w));
    return r.u;
}

__device__ __forceinline__ void bfu4_to_f8(uint4 u, float* f) {
    f[0] = __uint_as_float(u.x << 16); f[1] = __uint_as_float(u.x & 0xffff0000u);
    f[2] = __uint_as_float(u.y << 16); f[3] = __uint_as_float(u.y & 0xffff0000u);
    f[4] = __uint_as_float(u.z << 16); f[5] = __uint_as_float(u.z & 0xffff0000u);
    f[6] = __uint_as_float(u.w << 16); f[7] = __uint_as_float(u.w & 0xffff0000u);
}

__device__ __forceinline__ uint4 pack8(const float* v) {
    union { __hip_bfloat162 h[4]; uint4 u; } r;
#pragma unroll
    for (int j = 0; j < 4; ++j) r.h[j] = __float22bfloat162_rn(make_float2(v[2 * j], v[2 * j + 1]));
    return r.u;
}

__device__ __forceinline__ float sigf(float x) { return 1.f / (1.f + __expf(-x)); }
__device__ __forceinline__ float fast_tanh(float x) { return 1.f - 2.f / (__expf(2.f * x) + 1.f); }

#define PIPE_BAR_PRE_12() do {                                                \
    asm volatile("s_waitcnt vmcnt(12) lgkmcnt(0)" ::: "memory");              \
    __builtin_amdgcn_s_barrier();                                             \
    __builtin_amdgcn_sched_barrier(0);                                        \
} while (0)
#define PIPE_BAR_PRE_CNT()  do {                                              \
    asm volatile("s_waitcnt vmcnt(6) lgkmcnt(0)" ::: "memory");               \
    __builtin_amdgcn_s_barrier();                                             \
    __builtin_amdgcn_sched_barrier(0);                                        \
} while (0)
#define PIPE_BAR_PRE_ZERO() do {                                              \
    asm volatile("s_waitcnt vmcnt(0) lgkmcnt(0)" ::: "memory");               \
    __builtin_amdgcn_s_barrier();                                             \
    __builtin_amdgcn_sched_barrier(0);                                        \
} while (0)
#define PIPE_BAR_POST() do {                                                  \
    __builtin_amdgcn_sched_barrier(0);                                        \
    asm volatile("s_waitcnt lgkmcnt(0)" ::: "memory");                        \
    __builtin_amdgcn_s_barrier();                                             \
    __builtin_amdgcn_sched_barrier(0);                                        \
} while (0)

// One fp32->bf16 tile-major convert unit, t in [0, 926720).
__device__ __forceinline__ void convert_unit(int t,
    const float* __restrict__ x, const float* __restrict__ h_prev,
    const float* __restrict__ W_ih, const float* __restrict__ W_hh,
    const float* __restrict__ W_read, const float* __restrict__ W_write,
    const float* __restrict__ W_erase, const float* __restrict__ W_add,
    const float* __restrict__ W_out, const float* __restrict__ memory,
    u16* x_t, u16* ht_t, u16* wcat_t, u16* Wcat2_t, u16* Wo_rn, u16* memt)
{
    if (t < 32768) {  // x -> x_t[mt][oct8][row128]
        int r = t >> 4, c = (t & 15) * 4;
        cvt4(x + r * 64 + c, x_t + ((r >> 7) * 8 + (c >> 3)) * 1024 + (r & 127) * 8 + (c & 7));
        return;
    }
    t -= 32768;
    if (t < 262144) {  // h_prev -> ht_t[mt][oct64][row128]
        int r = t >> 7, c = (t & 127) * 4;
        cvt4(h_prev + r * 512 + c, ht_t + ((r >> 7) * 64 + (c >> 3)) * 1024 + (r & 127) * 8 + (c & 7));
        return;
    }
    t -= 262144;
    if (t < 65536) {  // W_ih (gate-interleave rows, col swap rp|x) -> wcat_t[bn][kt0][oct][row64]
        int r = t >> 5, c = (t & 31) * 4;
        int g = r >> 9, j = r & 511;
        int bn = j >> 4, row64 = (g << 4) + (j & 15);
        int cd = (c < 64) ? c + 64 : c - 64;
        cvt4(W_ih + r * 128 + c, wcat_t + (bn * 5) * 8192 + (cd >> 3) * 512 + row64 * 8 + (cd & 7));
        return;
    }
    t -= 65536;
    if (t < 262144) {  // W_hh -> wcat_t[bn][kt1..4][oct][row64]
        int r = t >> 7, c = (t & 127) * 4;
        int g = r >> 9, j = r & 511;
        int bn = j >> 4, row64 = (g << 4) + (j & 15);
        int cd = 128 + c;
        cvt4(W_hh + r * 512 + c, wcat_t + (bn * 5 + (cd >> 7)) * 8192 + ((cd >> 3) & 15) * 512 + row64 * 8 + (cd & 7));
        return;
    }
    t -= 262144;
    if (t < 131072) {  // W_read -> Wcat2_t bn 0..15
        int r = t >> 7, c = (t & 127) * 4;
        cvt4(W_read + t * 4, Wcat2_t + ((r >> 6) * 4 + (c >> 7)) * 8192 + ((c >> 3) & 15) * 512 + (r & 63) * 8 + (c & 7));
        return;
    }
    t -= 131072;
    if (t < 131072) {  // W_write -> bn 16..31
        int r = t >> 7, c = (t & 127) * 4;
        cvt4(W_write + t * 4, Wcat2_t + ((16 + (r >> 6)) * 4 + (c >> 7)) * 8192 + ((c >> 3) & 15) * 512 + (r & 63) * 8 + (c & 7));
        return;
    }
    t -= 131072;
    if (t < 8192) {  // W_erase -> bn 32
        int r = t >> 7, c = (t & 127) * 4;
        cvt4(W_erase + t * 4, Wcat2_t + (32 * 4 + (c >> 7)) * 8192 + ((c >> 3) & 15) * 512 + r * 8 + (c & 7));
        return;
    }
    t -= 8192;
    if (t < 8192) {  // W_add -> bn 33
        int r = t >> 7, c = (t & 127) * 4;
        cvt4(W_add + t * 4, Wcat2_t + (33 * 4 + (c >> 7)) * 8192 + ((c >> 3) & 15) * 512 + r * 8 + (c & 7));
        return;
    }
    t -= 8192;
    if (t < 9216) {  // W_out: h-part -> bn 34; rn-part -> Wo_rn
        int r = t / 144, c = (t % 144) * 4;
        if (c < 512)
            cvt4(W_out + r * 576 + c, Wcat2_t + (34 * 4 + (c >> 7)) * 8192 + ((c >> 3) & 15) * 512 + r * 8 + (c & 7));
        else
            cvt4(W_out + r * 576 + c, Wo_rn + r * 64 + (c - 512));
        return;
    }
    t -= 9216;
    {  // memory^T -> memt (64 x 1024)
        int v = t >> 8, m = (t & 255) * 4;
        pack_store4(memory[m * 64 + v], memory[(m + 1) * 64 + v],
                    memory[(m + 2) * 64 + v], memory[(m + 3) * 64 + v], memt + v * 1024 + m);
    }
}

// ---------------------------------------------------------------------------
// k_pre: blocks 0..127 = read_prev GEMM, FULL-K, BK=256 (16 rows x 64 cols,
// 4 staging rounds), writing bf16 directly in the gates A-tile fragment
// layout rpt[mt][oct8][row128][8]. Blocks 128..639 = grid-stride converts.
// ---------------------------------------------------------------------------
__global__ __launch_bounds__(256) void k_pre(
    const float* __restrict__ x, const float* __restrict__ h_prev, const float* __restrict__ rwp,
    const float* __restrict__ memory, const float* __restrict__ W_ih, const float* __restrict__ W_hh,
    const float* __restrict__ W_read, const float* __restrict__ W_write, const float* __restrict__ W_erase,
    const float* __restrict__ W_add, const float* __restrict__ W_out,
    u16* x_t, u16* ht_t, u16* wcat_t, u16* Wcat2_t, u16* Wo_rn, u16* memt, u16* rpt)
{
    __shared__ u16 As[16 * LDW2];   // 16 rows x 256 K (8.4 KB)
    __shared__ u16 Bs[64 * LDW2];   // 64 v x 256 m    (33.8 KB)
    const int tid = threadIdx.x;

    if (blockIdx.x < 128) {
        const int mb = blockIdx.x;
        const int w = tid >> 6, lane = tid & 63;
        const int lrow = lane & 15, lq = lane >> 4;
        const int m0 = mb * 16;
        f32x4 acc = {};
        for (int kt = 0; kt < 4; ++kt) {
            {   // As: 16 rows x 256 K (two cvt8u per thread)
                int r = tid >> 4, c = (tid & 15) * 8;
                *(uint4*)(&As[r * LDW2 + c])       = cvt8u(rwp + (m0 + r) * 1024 + kt * 256 + c);
                *(uint4*)(&As[r * LDW2 + c + 128]) = cvt8u(rwp + (m0 + r) * 1024 + kt * 256 + c + 128);
            }
#pragma unroll
            for (int j = 0; j < 16; ++j) {  // Bs: v-major 64 x 256 (m = tid)
                float4 q = *(const float4*)(memory + (kt * 256 + tid) * 64 + 4 * j);
                Bs[(4 * j + 0) * LDW2 + tid] = f2bf(q.x);
                Bs[(4 * j + 1) * LDW2 + tid] = f2bf(q.y);
                Bs[(4 * j + 2) * LDW2 + tid] = f2bf(q.z);
                Bs[(4 * j + 3) * LDW2 + tid] = f2bf(q.w);
            }
            __syncthreads();
#pragma unroll
            for (int kk = 0; kk < 256; kk += 32) {
                bf16x8 a = *(const bf16x8*)(&As[lrow * LDW2 + kk + 8 * lq]);
                bf16x8 b = *(const bf16x8*)(&Bs[(16 * w + lrow) * LDW2 + kk + 8 * lq]);
                acc = MFMA_BF16(a, b, acc);
            }
            __syncthreads();
        }
        // write bf16 in gates-A fragment layout: elem [row][v] ->
        // rpt[(row>>7)*8192 + (v>>3)*1024 + (row&127)*8 + (v&7)]
#pragma unroll
        for (int r = 0; r < 4; ++r) {
            int row = m0 + 4 * lq + r, v = 16 * w + lrow;
            rpt[(row >> 7) * 8192 + (v >> 3) * 1024 + (row & 127) * 8 + (v & 7)] = f2bf(acc[r]);
        }
        return;
    }

    for (int t = (blockIdx.x - 128) * 256 + tid; t < 926720; t += 512 * 256)
        convert_unit(t, x, h_prev, W_ih, W_hh, W_read, W_write, W_erase, W_add,
                     W_out, memory, x_t, ht_t, wcat_t, Wcat2_t, Wo_rn, memt);
}

// ---------------------------------------------------------------------------
// gates GEMM + fused LSTM. A-K = [rp(64) | x(64) | h(512)] = 10 BK=64 tiles.
// 3-deep LDS pipeline, prefetch distance 2, counted vmcnt(12).
// ---------------------------------------------------------------------------
__global__ __launch_bounds__(256) void k_gates(const u16* __restrict__ rpt, const u16* __restrict__ x_t,
                                               const u16* __restrict__ ht_t, const u16* __restrict__ wcat_t,
                                               const float* __restrict__ b_ih, const float* __restrict__ b_hh,
                                               const float* __restrict__ c_prev, u16* __restrict__ hrn_t)
{
    __shared__ u16 As[3][8192];   // 3 x (8 oct x 128 row x 8)  = 48 KB
    __shared__ u16 Bs[3][4096];   // 3 x (8 oct x  64 row x 8)  = 24 KB
    const int tid = threadIdx.x, w = tid >> 6, lane = tid & 63;
    const int lrow = lane & 15, lq = lane >> 4;
    const int mt = blockIdx.x, bn = blockIdx.y;
    const int m0 = mt * 128;
    f32x4 acc[2][4] = {};

#define STAGE_A(tn, bb) do {                                                   \
    const u16* asrc_ = ((tn) == 0) ? (rpt + mt * 8192)                         \
                     : ((tn) == 1) ? (x_t + mt * 8192)                         \
                     : (ht_t + mt * 65536 + ((tn) - 2) * 8192);                \
    _Pragma("unroll")                                                          \
    for (int i_ = 0; i_ < 4; ++i_)                                             \
        dma16(asrc_ + (i_ * 256 + tid) * 8, &As[(bb)][(i_ * 256 + w * 64) * 8]);\
} while (0)
#define STAGE_B(tn, bb) do {                                                   \
    _Pragma("unroll")                                                          \
    for (int i_ = 0; i_ < 2; ++i_)                                             \
        dma16(wcat_t + (bn * 5 + ((tn) >> 1)) * 8192 + ((tn) & 1) * 4096       \
                  + (i_ * 256 + tid) * 8, &Bs[(bb)][(i_ * 256 + w * 64) * 8]); \
} while (0)

    // prologue: stage tiles 0 and 1 (12 DMAs in flight)
    STAGE_A(0, 0); STAGE_B(0, 0);
    STAGE_A(1, 1); STAGE_B(1, 1);

#pragma unroll
    for (int t = 0; t < 10; ++t) {
        if (t < 8) {
            const int tn = t + 2, bb = tn % 3;
            STAGE_A(tn, bb); STAGE_B(tn, bb);   // 18 in flight
            PIPE_BAR_PRE_12();                  // retire tile t (2 newest stay)
        } else if (t == 8) {
            PIPE_BAR_PRE_CNT();                 // vmcnt(6): retire tile 8
        } else {
            PIPE_BAR_PRE_ZERO();                // tile 9
        }
        const int b = t % 3;
#pragma unroll
        for (int kk = 0; kk < 64; kk += 32) {
            const int ob = (kk >> 3) + lq;
            bf16x8 a0 = *(const bf16x8*)(&As[b][ob * 1024 + (32 * w + lrow) * 8]);
            bf16x8 a1 = *(const bf16x8*)(&As[b][ob * 1024 + (32 * w + 16 + lrow) * 8]);
            bf16x8 b0 = *(const bf16x8*)(&Bs[b][ob * 512 + (lrow) * 8]);
            bf16x8 b1 = *(const bf16x8*)(&Bs[b][ob * 512 + (16 + lrow) * 8]);
            bf16x8 b2 = *(const bf16x8*)(&Bs[b][ob * 512 + (32 + lrow) * 8]);
            bf16x8 b3 = *(const bf16x8*)(&Bs[b][ob * 512 + (48 + lrow) * 8]);
            acc[0][0] = MFMA_BF16(a0, b0, acc[0][0]);
            acc[0][1] = MFMA_BF16(a0, b1, acc[0][1]);
            acc[0][2] = MFMA_BF16(a0, b2, acc[0][2]);
            acc[0][3] = MFMA_BF16(a0, b3, acc[0][3]);
            acc[1][0] = MFMA_BF16(a1, b0, acc[1][0]);
            acc[1][1] = MFMA_BF16(a1, b1, acc[1][1]);
            acc[1][2] = MFMA_BF16(a1, b2, acc[1][2]);
            acc[1][3] = MFMA_BF16(a1, b3, acc[1][3]);
        }
        PIPE_BAR_POST();
    }
#undef STAGE_A
#undef STAGE_B

    const int j = bn * 16 + lrow;
    const float bI = b_ih[j] + b_hh[j];
    const float bF = b_ih[512 + j] + b_hh[512 + j];
    const float bG = b_ih[1024 + j] + b_hh[1024 + j];
    const float bO = b_ih[1536 + j] + b_hh[1536 + j];
#pragma unroll
    for (int mi = 0; mi < 2; ++mi)
#pragma unroll
        for (int r = 0; r < 4; ++r) {
            int row = m0 + 32 * w + 16 * mi + 4 * lq + r;
            float ig = sigf(acc[mi][0][r] + bI);
            float fg = sigf(acc[mi][1][r] + bF);
            float gg = fast_tanh(acc[mi][2][r] + bG);
            float og = sigf(acc[mi][3][r] + bO);
            float c = fg * c_prev[row * 512 + j] + ig * gg;
            // h -> tile-major hrn_t[mt][oct][row]
            hrn_t[(row >> 7) * 65536 + (j >> 3) * 1024 + (row & 127) * 8 + (j & 7)] =
                f2bf(og * fast_tanh(c));
        }
}

// ---------------------------------------------------------------------------
// heads: [pre_read | pre_write | erase | add | out_h] = h @ Wcat2^T + biases.
// grid (16, 35). 2-phase double-buffered pipeline, 8 BK=64 tiles (48 KB LDS
// keeps all 560 blocks co-resident at 3/CU -- do NOT deepen this one).
// ---------------------------------------------------------------------------
__global__ __launch_bounds__(256) void k_heads(const u16* __restrict__ hrn_t, const u16* __restrict__ Wcat2_t,
                                               const float* __restrict__ b_read, const float* __restrict__ b_write,
                                               const float* __restrict__ b_erase, const float* __restrict__ b_add,
                                               const float* __restrict__ b_out,
                                               u16* __restrict__ pre_r, u16* __restrict__ pre_w,
                                               float* __restrict__ erase, float* __restrict__ add,
                                               float* __restrict__ out)
{
    __shared__ u16 As[2][8192];
    __shared__ u16 Bs[2][4096];
    const int tid = threadIdx.x, w = tid >> 6, lane = tid & 63;
    const int lrow = lane & 15, lq = lane >> 4;
    const int mt = blockIdx.x, bn = blockIdx.y;
    const int m0 = mt * 128;
    f32x4 acc[2][4] = {};

    // prologue: stage tile 0
#pragma unroll
    for (int i = 0; i < 4; ++i)
        dma16(hrn_t + mt * 65536 + (i * 256 + tid) * 8, &As[0][(i * 256 + w * 64) * 8]);
#pragma unroll
    for (int i = 0; i < 2; ++i)
        dma16(Wcat2_t + (bn * 4) * 8192 + (i * 256 + tid) * 8, &Bs[0][(i * 256 + w * 64) * 8]);

#pragma unroll
    for (int t = 0; t < 8; ++t) {
        if (t < 7) {
            const int tn = t + 1, b = tn & 1;
#pragma unroll
            for (int i = 0; i < 4; ++i)
                dma16(hrn_t + mt * 65536 + tn * 8192 + (i * 256 + tid) * 8,
                      &As[b][(i * 256 + w * 64) * 8]);
#pragma unroll
            for (int i = 0; i < 2; ++i)
                dma16(Wcat2_t + (bn * 4 + (tn >> 1)) * 8192 + (tn & 1) * 4096 + (i * 256 + tid) * 8,
                      &Bs[b][(i * 256 + w * 64) * 8]);
            PIPE_BAR_PRE_CNT();
        } else {
            PIPE_BAR_PRE_ZERO();
        }
        const int b = t & 1;
#pragma unroll
        for (int kk = 0; kk < 64; kk += 32) {
            const int ob = (kk >> 3) + lq;
            bf16x8 a0 = *(const bf16x8*)(&As[b][ob * 1024 + (32 * w + lrow) * 8]);
            bf16x8 a1 = *(const bf16x8*)(&As[b][ob * 1024 + (32 * w + 16 + lrow) * 8]);
            bf16x8 b0 = *(const bf16x8*)(&Bs[b][ob * 512 + (lrow) * 8]);
            bf16x8 b1 = *(const bf16x8*)(&Bs[b][ob * 512 + (16 + lrow) * 8]);
            bf16x8 b2 = *(const bf16x8*)(&Bs[b][ob * 512 + (32 + lrow) * 8]);
            bf16x8 b3 = *(const bf16x8*)(&Bs[b][ob * 512 + (48 + lrow) * 8]);
            acc[0][0] = MFMA_BF16(a0, b0, acc[0][0]);
            acc[0][1] = MFMA_BF16(a0, b1, acc[0][1]);
            acc[0][2] = MFMA_BF16(a0, b2, acc[0][2]);
            acc[0][3] = MFMA_BF16(a0, b3, acc[0][3]);
            acc[1][0] = MFMA_BF16(a1, b0, acc[1][0]);
            acc[1][1] = MFMA_BF16(a1, b1, acc[1][1]);
            acc[1][2] = MFMA_BF16(a1, b2, acc[1][2]);
            acc[1][3] = MFMA_BF16(a1, b3, acc[1][3]);
        }
        PIPE_BAR_POST();
    }

#pragma unroll
    for (int mi = 0; mi < 2; ++mi)
#pragma unroll
        for (int nj = 0; nj < 4; ++nj)
#pragma unroll
            for (int r = 0; r < 4; ++r) {
                int row = m0 + 32 * w + 16 * mi + 4 * lq + r;
                int col = bn * 64 + 16 * nj + lrow;
                float v = acc[mi][nj][r];
                if (bn < 16)       pre_r[row * 1024 + col] = f2bf(v + b_read[col]);
                else if (bn < 32)  pre_w[row * 1024 + (col - 1024)] = f2bf(v + b_write[col - 1024]);
                else if (bn == 32) erase[row * 64 + (col - 2048)] = sigf(v + b_erase[col - 2048]);
                else if (bn == 33) add[row * 64 + (col - 2112)] = fast_tanh(v + b_add[col - 2112]);
                else               out[row * 64 + (col - 2176)] = v + b_out[col - 2176];
            }
}

// ---------------------------------------------------------------------------
// k_tail: 256 blocks = 128 m-blocks (16 rows) x 2 K-halves.
// dual softmax (redundant across halves) -> LDS; read_new GEMM (K=512);
// partial rn through Wo_rn^T; atomicAdd into out (seeded with out_h + b_out).
// ---------------------------------------------------------------------------
__global__ __launch_bounds__(256) void k_tail(const u16* __restrict__ pre_r, const u16* __restrict__ pre_w,
                                              const u16* __restrict__ memt, const u16* __restrict__ Wo_rn,
                                              const float* __restrict__ erase, const float* __restrict__ add,
                                              float* __restrict__ out)
{
    __shared__ u16 rwS[16 * SLDW];
    __shared__ u16 rw2S[16 * SLDW];
    __shared__ u16 BsP[64 * LDW];
    __shared__ u16 Ps[16 * 72];
    __shared__ float s_sh[16];
    const int tid = threadIdx.x, w = tid >> 6, lane = tid & 63;
    const int lrow = lane & 15, lq = lane >> 4;
    const int mb = blockIdx.x >> 1, kh = blockIdx.x & 1;
    const int m0 = mb * 16, k0 = kh * 512;

    {
        const int row = tid >> 4, c16 = tid & 15;
        const int row_g = m0 + row;
        const u16* prp = pre_r + row_g * 1024;
        const u16* pwp = pre_w + row_g * 1024;
        float vr[64], vw[64];
#pragma unroll
        for (int q = 0; q < 8; ++q) {
            bfu4_to_f8(*(const uint4*)(prp + q * 128 + c16 * 8), vr + 8 * q);
            bfu4_to_f8(*(const uint4*)(pwp + q * 128 + c16 * 8), vw + 8 * q);
        }
        float mr = vr[0], mw = vw[0];
#pragma unroll
        for (int i = 1; i < 64; ++i) { mr = fmaxf(mr, vr[i]); mw = fmaxf(mw, vw[i]); }
#pragma unroll
        for (int o = 1; o < 16; o <<= 1) {
            mr = fmaxf(mr, __shfl_xor(mr, o, 64));
            mw = fmaxf(mw, __shfl_xor(mw, o, 64));
        }
        float sr = 0.f, sw = 0.f;
#pragma unroll
        for (int i = 0; i < 64; ++i) {
            vr[i] = __expf(vr[i] - mr); sr += vr[i];
            vw[i] = __expf(vw[i] - mw); sw += vw[i];
        }
#pragma unroll
        for (int o = 1; o < 16; o <<= 1) {
            sr += __shfl_xor(sr, o, 64);
            sw += __shfl_xor(sw, o, 64);
        }
        const float isr = 1.f / sr, isw = 1.f / sw;
        float ss = 0.f;
#pragma unroll
        for (int q = 0; q < 8; ++q) {
            float a8[8], r8[8];
#pragma unroll
            for (int i = 0; i < 8; ++i) {
                float a = vr[8 * q + i] * isr;
                float r2 = a * (vw[8 * q + i] * isw);
                a8[i] = a; r8[i] = r2;
                ss += r2;
            }
            if ((q >> 2) == kh) {
                int cb = (q - 4 * kh) * 128 + c16 * 8;
                *(uint4*)(&rwS[row * SLDW + cb])  = pack8(a8);
                *(uint4*)(&rw2S[row * SLDW + cb]) = pack8(r8);
            }
        }
#pragma unroll
        for (int o = 1; o < 16; o <<= 1) ss += __shfl_xor(ss, o, 64);
        if (c16 == 0) s_sh[row] = ss;
    }
    __syncthreads();

    f32x4 acc1 = {}, acc2 = {};
    for (int kt = 0; kt < 4; ++kt) {
#pragma unroll
        for (int i = 0; i < 4; ++i) {
            int idx = i * 256 + tid, r = idx >> 4, c = (idx & 15) * 8;
            *(uint4*)(&BsP[r * LDW + c]) = *(const uint4*)(memt + r * 1024 + k0 + kt * 128 + c);
        }
        __syncthreads();
#pragma unroll
        for (int kk = 0; kk < 128; kk += 32) {
            bf16x8 a1 = *(const bf16x8*)(&rwS[lrow * SLDW + kt * 128 + kk + 8 * lq]);
            bf16x8 a2 = *(const bf16x8*)(&rw2S[lrow * SLDW + kt * 128 + kk + 8 * lq]);
            bf16x8 b  = *(const bf16x8*)(&BsP[(16 * w + lrow) * LDW + kk + 8 * lq]);
            acc1 = MFMA_BF16(a1, b, acc1);
            acc2 = MFMA_BF16(a2, b, acc2);
        }
        __syncthreads();
    }

#pragma unroll
    for (int r = 0; r < 4; ++r) {
        int row_l = 4 * lq + r, col = 16 * w + lrow;
        int row_g = m0 + row_l;
        float p = acc1[r] - erase[row_g * 64 + col] * acc2[r];
        if (kh == 0) p += add[row_g * 64 + col] * s_sh[row_l];
        Ps[row_l * 72 + col] = f2bf(p);
    }
#pragma unroll
    for (int i = 0; i < 2; ++i) {
        int idx = i * 256 + tid, r = idx >> 3, c = (idx & 7) * 8;
        *(uint4*)(&BsP[r * LDW + c]) = *(const uint4*)(Wo_rn + r * 64 + c);
    }
    __syncthreads();

    f32x4 acc3 = {};
#pragma unroll
    for (int kk = 0; kk < 64; kk += 32) {
        bf16x8 a = *(const bf16x8*)(&Ps[lrow * 72 + kk + 8 * lq]);
        bf16x8 b = *(const bf16x8*)(&BsP[(16 * w + lrow) * LDW + kk + 8 * lq]);
        acc3 = MFMA_BF16(a, b, acc3);
    }
#pragma unroll
    for (int r = 0; r < 4; ++r) {
        int row_g = m0 + 4 * lq + r, col = 16 * w + lrow;
        atomicAdd(&out[row_g * 64 + col], acc3[r]);
    }
}

extern "C" void kernel_launch(void* const* d_in, const int* in_sizes, int n_in,
                              void* d_out, int out_size, void* d_ws, size_t ws_size,
                              hipStream_t stream)
{
    const float* x        = (const float*)d_in[0];
    const float* h_prev   = (const float*)d_in[1];
    const float* c_prev   = (const float*)d_in[2];
    const float* rwp      = (const float*)d_in[3];
    const float* memory   = (const float*)d_in[4];
    const float* W_ih     = (const float*)d_in[5];
    const float* b_ih     = (const float*)d_in[6];
    const float* W_hh     = (const float*)d_in[7];
    const float* b_hh     = (const float*)d_in[8];
    const float* W_read   = (const float*)d_in[9];
    const float* b_read   = (const float*)d_in[10];
    const float* W_write  = (const float*)d_in[11];
    const float* b_write  = (const float*)d_in[12];
    const float* W_erase  = (const float*)d_in[13];
    const float* b_erase  = (const float*)d_in[14];
    const float* W_add    = (const float*)d_in[15];
    const float* b_add    = (const float*)d_in[16];
    const float* W_out    = (const float*)d_in[17];
    const float* b_out    = (const float*)d_in[18];
    float* out = (float*)d_out;

    char* wsp = (char*)d_ws;
    u16*   x_t     = (u16*)(wsp + 0);           // 16 x 8oct x 128row x 8  (256 KB)
    u16*   ht_t    = (u16*)(wsp + 262144);      // 16 x 64oct x 128row x 8 (2 MB)
    u16*   wcat_t  = (u16*)(wsp + 2359296);     // 32bn x 5kt x 16oct x 64row x 8
    u16*   memt    = (u16*)(wsp + 4980736);     // 64 x 1024 bf16 memory^T
    u16*   Wcat2_t = (u16*)(wsp + 5111808);     // 35bn x 4kt x 16oct x 64row x 8
    u16*   Wo_rn   = (u16*)(wsp + 7405568);     // 64x64 bf16
    u16*   rpt     = (u16*)(wsp + 7413760);     // 16mt x 8oct x 128row x 8 bf16 (256 KB)
    u16*   hrn_t   = (u16*)(wsp + 9510912);     // 16 x 64oct x 128row x 8 (2 MB)
    u16*   pre_r   = (u16*)(wsp + 11608064);    // 2048x1024 bf16
    u16*   pre_w   = (u16*)(wsp + 15802368);    // 2048x1024 bf16
    float* erase   = (float*)(wsp + 19996672);  // 2048x64 fp32
    float* add     = (float*)(wsp + 20520960);  // 2048x64 fp32

    k_pre<<<640, 256, 0, stream>>>(x, h_prev, rwp, memory, W_ih, W_hh, W_read, W_write,
                                   W_erase, W_add, W_out,
                                   x_t, ht_t, wcat_t, Wcat2_t, Wo_rn, memt, rpt);
    k_gates<<<dim3(16, 32), 256, 0, stream>>>(rpt, x_t, ht_t, wcat_t, b_ih, b_hh, c_prev, hrn_t);
    k_heads<<<dim3(16, 35), 256, 0, stream>>>(hrn_t, Wcat2_t, b_read, b_write, b_erase, b_add, b_out,
                                              pre_r, pre_w, erase, add, out);
    k_tail<<<256, 256, 0, stream>>>(pre_r, pre_w, memt, Wo_rn, erase, add, out);
}

// Round 11
// 152.818 us; speedup vs baseline: 1.0027x; 1.0027x over previous
//
#include <hip/hip_runtime.h>
#include <hip/hip_bf16.h>

// NTM cell on MI355X. B=2048, IN=64, CTRL=512, M=1024, V=64, OUT=64.
// 4 dispatches. FINAL (r9-optimum revert): r10's BK=256 k_pre regressed
// (+1.8us, staging-burst-bound not round-count-bound) -> k_pre back to
// BK=128 x 8 rounds. k_gates: 3-deep LDS pipeline, prefetch distance 2,
// counted vmcnt(12) (r9, -2.7us). k_pre GEMM writes bf16 full-K result
// directly in gates A-fragment layout (r8, -2.7us). k_heads 2-deep
// (560-block co-residency bound). k_tail unchanged.
// Session floor analysis: dur = ~88us harness poison-fills (fixed) +
// ~63us controllable (4 dep-forced launches, latency-bound; device-side
// grid barriers measured slower in r3-r6).

typedef unsigned short u16;
typedef __attribute__((ext_vector_type(8))) short bf16x8;
typedef __attribute__((ext_vector_type(4))) float f32x4;

#define MFMA_BF16(a, b, c) __builtin_amdgcn_mfma_f32_16x16x32_bf16((a), (b), (c), 0, 0, 0)
#define LDW 136
#define SLDW 520

__device__ __forceinline__ void dma16(const void* g, void* l) {
    __builtin_amdgcn_global_load_lds(
        (const __attribute__((address_space(1))) unsigned int*)g,
        (__attribute__((address_space(3))) unsigned int*)l, 16, 0, 0);
}

__device__ __forceinline__ u16 f2bf(float f) {
    union { float f; unsigned int u; } a; a.f = f;
    return (u16)((a.u + 0x7FFFu + ((a.u >> 16) & 1u)) >> 16);
}

__device__ __forceinline__ void pack_store4(float a0, float a1, float a2, float a3, u16* d) {
    union { __hip_bfloat162 h[2]; uint2 u; } cv;
    cv.h[0] = __float22bfloat162_rn(make_float2(a0, a1));
    cv.h[1] = __float22bfloat162_rn(make_float2(a2, a3));
    *(uint2*)d = cv.u;
}

__device__ __forceinline__ void cvt4(const float* __restrict__ s, u16* __restrict__ d) {
    float4 v = *(const float4*)s;
    pack_store4(v.x, v.y, v.z, v.w, d);
}

__device__ __forceinline__ uint4 cvt8u(const float* __restrict__ s) {
    float4 v0 = *(const float4*)(s);
    float4 v1 = *(const float4*)(s + 4);
    union { __hip_bfloat162 h[4]; uint4 u; } r;
    r.h[0] = __float22bfloat162_rn(make_float2(v0.x, v0.y));
    r.h[1] = __float22bfloat162_rn(make_float2(v0.z, v0.w));
    r.h[2] = __float22bfloat162_rn(make_float2(v1.x, v1.y));
    r.h[3] = __float22bfloat162_rn(make_float2(v1.z, v1.w));
    return r.u;
}

__device__ __forceinline__ void bfu4_to_f8(uint4 u, float* f) {
    f[0] = __uint_as_float(u.x << 16); f[1] = __uint_as_float(u.x & 0xffff0000u);
    f[2] = __uint_as_float(u.y << 16); f[3] = __uint_as_float(u.y & 0xffff0000u);
    f[4] = __uint_as_float(u.z << 16); f[5] = __uint_as_float(u.z & 0xffff0000u);
    f[6] = __uint_as_float(u.w << 16); f[7] = __uint_as_float(u.w & 0xffff0000u);
}

__device__ __forceinline__ uint4 pack8(const float* v) {
    union { __hip_bfloat162 h[4]; uint4 u; } r;
#pragma unroll
    for (int j = 0; j < 4; ++j) r.h[j] = __float22bfloat162_rn(make_float2(v[2 * j], v[2 * j + 1]));
    return r.u;
}

__device__ __forceinline__ float sigf(float x) { return 1.f / (1.f + __expf(-x)); }
__device__ __forceinline__ float fast_tanh(float x) { return 1.f - 2.f / (__expf(2.f * x) + 1.f); }

#define PIPE_BAR_PRE_12() do {                                                \
    asm volatile("s_waitcnt vmcnt(12) lgkmcnt(0)" ::: "memory");              \
    __builtin_amdgcn_s_barrier();                                             \
    __builtin_amdgcn_sched_barrier(0);                                        \
} while (0)
#define PIPE_BAR_PRE_CNT()  do {                                              \
    asm volatile("s_waitcnt vmcnt(6) lgkmcnt(0)" ::: "memory");               \
    __builtin_amdgcn_s_barrier();                                             \
    __builtin_amdgcn_sched_barrier(0);                                        \
} while (0)
#define PIPE_BAR_PRE_ZERO() do {                                              \
    asm volatile("s_waitcnt vmcnt(0) lgkmcnt(0)" ::: "memory");               \
    __builtin_amdgcn_s_barrier();                                             \
    __builtin_amdgcn_sched_barrier(0);                                        \
} while (0)
#define PIPE_BAR_POST() do {                                                  \
    __builtin_amdgcn_sched_barrier(0);                                        \
    asm volatile("s_waitcnt lgkmcnt(0)" ::: "memory");                        \
    __builtin_amdgcn_s_barrier();                                             \
    __builtin_amdgcn_sched_barrier(0);                                        \
} while (0)

// One fp32->bf16 tile-major convert unit, t in [0, 926720).
__device__ __forceinline__ void convert_unit(int t,
    const float* __restrict__ x, const float* __restrict__ h_prev,
    const float* __restrict__ W_ih, const float* __restrict__ W_hh,
    const float* __restrict__ W_read, const float* __restrict__ W_write,
    const float* __restrict__ W_erase, const float* __restrict__ W_add,
    const float* __restrict__ W_out, const float* __restrict__ memory,
    u16* x_t, u16* ht_t, u16* wcat_t, u16* Wcat2_t, u16* Wo_rn, u16* memt)
{
    if (t < 32768) {  // x -> x_t[mt][oct8][row128]
        int r = t >> 4, c = (t & 15) * 4;
        cvt4(x + r * 64 + c, x_t + ((r >> 7) * 8 + (c >> 3)) * 1024 + (r & 127) * 8 + (c & 7));
        return;
    }
    t -= 32768;
    if (t < 262144) {  // h_prev -> ht_t[mt][oct64][row128]
        int r = t >> 7, c = (t & 127) * 4;
        cvt4(h_prev + r * 512 + c, ht_t + ((r >> 7) * 64 + (c >> 3)) * 1024 + (r & 127) * 8 + (c & 7));
        return;
    }
    t -= 262144;
    if (t < 65536) {  // W_ih (gate-interleave rows, col swap rp|x) -> wcat_t[bn][kt0][oct][row64]
        int r = t >> 5, c = (t & 31) * 4;
        int g = r >> 9, j = r & 511;
        int bn = j >> 4, row64 = (g << 4) + (j & 15);
        int cd = (c < 64) ? c + 64 : c - 64;
        cvt4(W_ih + r * 128 + c, wcat_t + (bn * 5) * 8192 + (cd >> 3) * 512 + row64 * 8 + (cd & 7));
        return;
    }
    t -= 65536;
    if (t < 262144) {  // W_hh -> wcat_t[bn][kt1..4][oct][row64]
        int r = t >> 7, c = (t & 127) * 4;
        int g = r >> 9, j = r & 511;
        int bn = j >> 4, row64 = (g << 4) + (j & 15);
        int cd = 128 + c;
        cvt4(W_hh + r * 512 + c, wcat_t + (bn * 5 + (cd >> 7)) * 8192 + ((cd >> 3) & 15) * 512 + row64 * 8 + (cd & 7));
        return;
    }
    t -= 262144;
    if (t < 131072) {  // W_read -> Wcat2_t bn 0..15
        int r = t >> 7, c = (t & 127) * 4;
        cvt4(W_read + t * 4, Wcat2_t + ((r >> 6) * 4 + (c >> 7)) * 8192 + ((c >> 3) & 15) * 512 + (r & 63) * 8 + (c & 7));
        return;
    }
    t -= 131072;
    if (t < 131072) {  // W_write -> bn 16..31
        int r = t >> 7, c = (t & 127) * 4;
        cvt4(W_write + t * 4, Wcat2_t + ((16 + (r >> 6)) * 4 + (c >> 7)) * 8192 + ((c >> 3) & 15) * 512 + (r & 63) * 8 + (c & 7));
        return;
    }
    t -= 131072;
    if (t < 8192) {  // W_erase -> bn 32
        int r = t >> 7, c = (t & 127) * 4;
        cvt4(W_erase + t * 4, Wcat2_t + (32 * 4 + (c >> 7)) * 8192 + ((c >> 3) & 15) * 512 + r * 8 + (c & 7));
        return;
    }
    t -= 8192;
    if (t < 8192) {  // W_add -> bn 33
        int r = t >> 7, c = (t & 127) * 4;
        cvt4(W_add + t * 4, Wcat2_t + (33 * 4 + (c >> 7)) * 8192 + ((c >> 3) & 15) * 512 + r * 8 + (c & 7));
        return;
    }
    t -= 8192;
    if (t < 9216) {  // W_out: h-part -> bn 34; rn-part -> Wo_rn
        int r = t / 144, c = (t % 144) * 4;
        if (c < 512)
            cvt4(W_out + r * 576 + c, Wcat2_t + (34 * 4 + (c >> 7)) * 8192 + ((c >> 3) & 15) * 512 + r * 8 + (c & 7));
        else
            cvt4(W_out + r * 576 + c, Wo_rn + r * 64 + (c - 512));
        return;
    }
    t -= 9216;
    {  // memory^T -> memt (64 x 1024)
        int v = t >> 8, m = (t & 255) * 4;
        pack_store4(memory[m * 64 + v], memory[(m + 1) * 64 + v],
                    memory[(m + 2) * 64 + v], memory[(m + 3) * 64 + v], memt + v * 1024 + m);
    }
}

// ---------------------------------------------------------------------------
// k_pre: blocks 0..127 = read_prev GEMM, FULL-K (16 rows x 64 cols x K=1024
// per block, 8 staging rounds; BK=128 measured faster than BK=256 in r10),
// writing bf16 directly in the gates A-tile fragment layout
// rpt[mt][oct8][row128][8]. Blocks 128..639 = grid-stride converts.
// ---------------------------------------------------------------------------
__global__ __launch_bounds__(256) void k_pre(
    const float* __restrict__ x, const float* __restrict__ h_prev, const float* __restrict__ rwp,
    const float* __restrict__ memory, const float* __restrict__ W_ih, const float* __restrict__ W_hh,
    const float* __restrict__ W_read, const float* __restrict__ W_write, const float* __restrict__ W_erase,
    const float* __restrict__ W_add, const float* __restrict__ W_out,
    u16* x_t, u16* ht_t, u16* wcat_t, u16* Wcat2_t, u16* Wo_rn, u16* memt, u16* rpt)
{
    __shared__ u16 As[64 * LDW];
    __shared__ u16 Bs[64 * LDW];
    const int tid = threadIdx.x;

    if (blockIdx.x < 128) {
        const int mb = blockIdx.x;
        const int w = tid >> 6, lane = tid & 63;
        const int lrow = lane & 15, lq = lane >> 4;
        const int m0 = mb * 16;
        const int m_loc = tid >> 1, v0 = (tid & 1) * 32;
        f32x4 acc = {};
        for (int kt = 0; kt < 8; ++kt) {
            {   // As: 16 rows x 128 K (one cvt8u per thread)
                int r = tid >> 4, c = (tid & 15) * 8;
                *(uint4*)(&As[r * LDW + c]) = cvt8u(rwp + (m0 + r) * 1024 + kt * 128 + c);
            }
#pragma unroll
            for (int j = 0; j < 8; ++j) {  // Bs: v-major 64 x 128
                float4 q = *(const float4*)(memory + (kt * 128 + m_loc) * 64 + v0 + 4 * j);
                Bs[(v0 + 4 * j + 0) * LDW + m_loc] = f2bf(q.x);
                Bs[(v0 + 4 * j + 1) * LDW + m_loc] = f2bf(q.y);
                Bs[(v0 + 4 * j + 2) * LDW + m_loc] = f2bf(q.z);
                Bs[(v0 + 4 * j + 3) * LDW + m_loc] = f2bf(q.w);
            }
            __syncthreads();
#pragma unroll
            for (int kk = 0; kk < 128; kk += 32) {
                bf16x8 a = *(const bf16x8*)(&As[lrow * LDW + kk + 8 * lq]);
                bf16x8 b = *(const bf16x8*)(&Bs[(16 * w + lrow) * LDW + kk + 8 * lq]);
                acc = MFMA_BF16(a, b, acc);
            }
            __syncthreads();
        }
        // write bf16 in gates-A fragment layout: elem [row][v] ->
        // rpt[(row>>7)*8192 + (v>>3)*1024 + (row&127)*8 + (v&7)]
#pragma unroll
        for (int r = 0; r < 4; ++r) {
            int row = m0 + 4 * lq + r, v = 16 * w + lrow;
            rpt[(row >> 7) * 8192 + (v >> 3) * 1024 + (row & 127) * 8 + (v & 7)] = f2bf(acc[r]);
        }
        return;
    }

    for (int t = (blockIdx.x - 128) * 256 + tid; t < 926720; t += 512 * 256)
        convert_unit(t, x, h_prev, W_ih, W_hh, W_read, W_write, W_erase, W_add,
                     W_out, memory, x_t, ht_t, wcat_t, Wcat2_t, Wo_rn, memt);
}

// ---------------------------------------------------------------------------
// gates GEMM + fused LSTM. A-K = [rp(64) | x(64) | h(512)] = 10 BK=64 tiles.
// 3-deep LDS pipeline, prefetch distance 2, counted vmcnt(12).
// ---------------------------------------------------------------------------
__global__ __launch_bounds__(256) void k_gates(const u16* __restrict__ rpt, const u16* __restrict__ x_t,
                                               const u16* __restrict__ ht_t, const u16* __restrict__ wcat_t,
                                               const float* __restrict__ b_ih, const float* __restrict__ b_hh,
                                               const float* __restrict__ c_prev, u16* __restrict__ hrn_t)
{
    __shared__ u16 As[3][8192];   // 3 x (8 oct x 128 row x 8)  = 48 KB
    __shared__ u16 Bs[3][4096];   // 3 x (8 oct x  64 row x 8)  = 24 KB
    const int tid = threadIdx.x, w = tid >> 6, lane = tid & 63;
    const int lrow = lane & 15, lq = lane >> 4;
    const int mt = blockIdx.x, bn = blockIdx.y;
    const int m0 = mt * 128;
    f32x4 acc[2][4] = {};

#define STAGE_A(tn, bb) do {                                                   \
    const u16* asrc_ = ((tn) == 0) ? (rpt + mt * 8192)                         \
                     : ((tn) == 1) ? (x_t + mt * 8192)                         \
                     : (ht_t + mt * 65536 + ((tn) - 2) * 8192);                \
    _Pragma("unroll")                                                          \
    for (int i_ = 0; i_ < 4; ++i_)                                             \
        dma16(asrc_ + (i_ * 256 + tid) * 8, &As[(bb)][(i_ * 256 + w * 64) * 8]);\
} while (0)
#define STAGE_B(tn, bb) do {                                                   \
    _Pragma("unroll")                                                          \
    for (int i_ = 0; i_ < 2; ++i_)                                             \
        dma16(wcat_t + (bn * 5 + ((tn) >> 1)) * 8192 + ((tn) & 1) * 4096       \
                  + (i_ * 256 + tid) * 8, &Bs[(bb)][(i_ * 256 + w * 64) * 8]); \
} while (0)

    // prologue: stage tiles 0 and 1 (12 DMAs in flight)
    STAGE_A(0, 0); STAGE_B(0, 0);
    STAGE_A(1, 1); STAGE_B(1, 1);

#pragma unroll
    for (int t = 0; t < 10; ++t) {
        if (t < 8) {
            const int tn = t + 2, bb = tn % 3;
            STAGE_A(tn, bb); STAGE_B(tn, bb);   // 18 in flight
            PIPE_BAR_PRE_12();                  // retire tile t (2 newest stay)
        } else if (t == 8) {
            PIPE_BAR_PRE_CNT();                 // vmcnt(6): retire tile 8
        } else {
            PIPE_BAR_PRE_ZERO();                // tile 9
        }
        const int b = t % 3;
#pragma unroll
        for (int kk = 0; kk < 64; kk += 32) {
            const int ob = (kk >> 3) + lq;
            bf16x8 a0 = *(const bf16x8*)(&As[b][ob * 1024 + (32 * w + lrow) * 8]);
            bf16x8 a1 = *(const bf16x8*)(&As[b][ob * 1024 + (32 * w + 16 + lrow) * 8]);
            bf16x8 b0 = *(const bf16x8*)(&Bs[b][ob * 512 + (lrow) * 8]);
            bf16x8 b1 = *(const bf16x8*)(&Bs[b][ob * 512 + (16 + lrow) * 8]);
            bf16x8 b2 = *(const bf16x8*)(&Bs[b][ob * 512 + (32 + lrow) * 8]);
            bf16x8 b3 = *(const bf16x8*)(&Bs[b][ob * 512 + (48 + lrow) * 8]);
            acc[0][0] = MFMA_BF16(a0, b0, acc[0][0]);
            acc[0][1] = MFMA_BF16(a0, b1, acc[0][1]);
            acc[0][2] = MFMA_BF16(a0, b2, acc[0][2]);
            acc[0][3] = MFMA_BF16(a0, b3, acc[0][3]);
            acc[1][0] = MFMA_BF16(a1, b0, acc[1][0]);
            acc[1][1] = MFMA_BF16(a1, b1, acc[1][1]);
            acc[1][2] = MFMA_BF16(a1, b2, acc[1][2]);
            acc[1][3] = MFMA_BF16(a1, b3, acc[1][3]);
        }
        PIPE_BAR_POST();
    }
#undef STAGE_A
#undef STAGE_B

    const int j = bn * 16 + lrow;
    const float bI = b_ih[j] + b_hh[j];
    const float bF = b_ih[512 + j] + b_hh[512 + j];
    const float bG = b_ih[1024 + j] + b_hh[1024 + j];
    const float bO = b_ih[1536 + j] + b_hh[1536 + j];
#pragma unroll
    for (int mi = 0; mi < 2; ++mi)
#pragma unroll
        for (int r = 0; r < 4; ++r) {
            int row = m0 + 32 * w + 16 * mi + 4 * lq + r;
            float ig = sigf(acc[mi][0][r] + bI);
            float fg = sigf(acc[mi][1][r] + bF);
            float gg = fast_tanh(acc[mi][2][r] + bG);
            float og = sigf(acc[mi][3][r] + bO);
            float c = fg * c_prev[row * 512 + j] + ig * gg;
            // h -> tile-major hrn_t[mt][oct][row]
            hrn_t[(row >> 7) * 65536 + (j >> 3) * 1024 + (row & 127) * 8 + (j & 7)] =
                f2bf(og * fast_tanh(c));
        }
}

// ---------------------------------------------------------------------------
// heads: [pre_read | pre_write | erase | add | out_h] = h @ Wcat2^T + biases.
// grid (16, 35). 2-phase double-buffered pipeline, 8 BK=64 tiles (48 KB LDS
// keeps all 560 blocks co-resident at 3/CU -- do NOT deepen this one).
// ---------------------------------------------------------------------------
__global__ __launch_bounds__(256) void k_heads(const u16* __restrict__ hrn_t, const u16* __restrict__ Wcat2_t,
                                               const float* __restrict__ b_read, const float* __restrict__ b_write,
                                               const float* __restrict__ b_erase, const float* __restrict__ b_add,
                                               const float* __restrict__ b_out,
                                               u16* __restrict__ pre_r, u16* __restrict__ pre_w,
                                               float* __restrict__ erase, float* __restrict__ add,
                                               float* __restrict__ out)
{
    __shared__ u16 As[2][8192];
    __shared__ u16 Bs[2][4096];
    const int tid = threadIdx.x, w = tid >> 6, lane = tid & 63;
    const int lrow = lane & 15, lq = lane >> 4;
    const int mt = blockIdx.x, bn = blockIdx.y;
    const int m0 = mt * 128;
    f32x4 acc[2][4] = {};

    // prologue: stage tile 0
#pragma unroll
    for (int i = 0; i < 4; ++i)
        dma16(hrn_t + mt * 65536 + (i * 256 + tid) * 8, &As[0][(i * 256 + w * 64) * 8]);
#pragma unroll
    for (int i = 0; i < 2; ++i)
        dma16(Wcat2_t + (bn * 4) * 8192 + (i * 256 + tid) * 8, &Bs[0][(i * 256 + w * 64) * 8]);

#pragma unroll
    for (int t = 0; t < 8; ++t) {
        if (t < 7) {
            const int tn = t + 1, b = tn & 1;
#pragma unroll
            for (int i = 0; i < 4; ++i)
                dma16(hrn_t + mt * 65536 + tn * 8192 + (i * 256 + tid) * 8,
                      &As[b][(i * 256 + w * 64) * 8]);
#pragma unroll
            for (int i = 0; i < 2; ++i)
                dma16(Wcat2_t + (bn * 4 + (tn >> 1)) * 8192 + (tn & 1) * 4096 + (i * 256 + tid) * 8,
                      &Bs[b][(i * 256 + w * 64) * 8]);
            PIPE_BAR_PRE_CNT();
        } else {
            PIPE_BAR_PRE_ZERO();
        }
        const int b = t & 1;
#pragma unroll
        for (int kk = 0; kk < 64; kk += 32) {
            const int ob = (kk >> 3) + lq;
            bf16x8 a0 = *(const bf16x8*)(&As[b][ob * 1024 + (32 * w + lrow) * 8]);
            bf16x8 a1 = *(const bf16x8*)(&As[b][ob * 1024 + (32 * w + 16 + lrow) * 8]);
            bf16x8 b0 = *(const bf16x8*)(&Bs[b][ob * 512 + (lrow) * 8]);
            bf16x8 b1 = *(const bf16x8*)(&Bs[b][ob * 512 + (16 + lrow) * 8]);
            bf16x8 b2 = *(const bf16x8*)(&Bs[b][ob * 512 + (32 + lrow) * 8]);
            bf16x8 b3 = *(const bf16x8*)(&Bs[b][ob * 512 + (48 + lrow) * 8]);
            acc[0][0] = MFMA_BF16(a0, b0, acc[0][0]);
            acc[0][1] = MFMA_BF16(a0, b1, acc[0][1]);
            acc[0][2] = MFMA_BF16(a0, b2, acc[0][2]);
            acc[0][3] = MFMA_BF16(a0, b3, acc[0][3]);
            acc[1][0] = MFMA_BF16(a1, b0, acc[1][0]);
            acc[1][1] = MFMA_BF16(a1, b1, acc[1][1]);
            acc[1][2] = MFMA_BF16(a1, b2, acc[1][2]);
            acc[1][3] = MFMA_BF16(a1, b3, acc[1][3]);
        }
        PIPE_BAR_POST();
    }

#pragma unroll
    for (int mi = 0; mi < 2; ++mi)
#pragma unroll
        for (int nj = 0; nj < 4; ++nj)
#pragma unroll
            for (int r = 0; r < 4; ++r) {
                int row = m0 + 32 * w + 16 * mi + 4 * lq + r;
                int col = bn * 64 + 16 * nj + lrow;
                float v = acc[mi][nj][r];
                if (bn < 16)       pre_r[row * 1024 + col] = f2bf(v + b_read[col]);
                else if (bn < 32)  pre_w[row * 1024 + (col - 1024)] = f2bf(v + b_write[col - 1024]);
                else if (bn == 32) erase[row * 64 + (col - 2048)] = sigf(v + b_erase[col - 2048]);
                else if (bn == 33) add[row * 64 + (col - 2112)] = fast_tanh(v + b_add[col - 2112]);
                else               out[row * 64 + (col - 2176)] = v + b_out[col - 2176];
            }
}

// ---------------------------------------------------------------------------
// k_tail: 256 blocks = 128 m-blocks (16 rows) x 2 K-halves.
// dual softmax (redundant across halves) -> LDS; read_new GEMM (K=512);
// partial rn through Wo_rn^T; atomicAdd into out (seeded with out_h + b_out).
// ---------------------------------------------------------------------------
__global__ __launch_bounds__(256) void k_tail(const u16* __restrict__ pre_r, const u16* __restrict__ pre_w,
                                              const u16* __restrict__ memt, const u16* __restrict__ Wo_rn,
                                              const float* __restrict__ erase, const float* __restrict__ add,
                                              float* __restrict__ out)
{
    __shared__ u16 rwS[16 * SLDW];
    __shared__ u16 rw2S[16 * SLDW];
    __shared__ u16 BsP[64 * LDW];
    __shared__ u16 Ps[16 * 72];
    __shared__ float s_sh[16];
    const int tid = threadIdx.x, w = tid >> 6, lane = tid & 63;
    const int lrow = lane & 15, lq = lane >> 4;
    const int mb = blockIdx.x >> 1, kh = blockIdx.x & 1;
    const int m0 = mb * 16, k0 = kh * 512;

    {
        const int row = tid >> 4, c16 = tid & 15;
        const int row_g = m0 + row;
        const u16* prp = pre_r + row_g * 1024;
        const u16* pwp = pre_w + row_g * 1024;
        float vr[64], vw[64];
#pragma unroll
        for (int q = 0; q < 8; ++q) {
            bfu4_to_f8(*(const uint4*)(prp + q * 128 + c16 * 8), vr + 8 * q);
            bfu4_to_f8(*(const uint4*)(pwp + q * 128 + c16 * 8), vw + 8 * q);
        }
        float mr = vr[0], mw = vw[0];
#pragma unroll
        for (int i = 1; i < 64; ++i) { mr = fmaxf(mr, vr[i]); mw = fmaxf(mw, vw[i]); }
#pragma unroll
        for (int o = 1; o < 16; o <<= 1) {
            mr = fmaxf(mr, __shfl_xor(mr, o, 64));
            mw = fmaxf(mw, __shfl_xor(mw, o, 64));
        }
        float sr = 0.f, sw = 0.f;
#pragma unroll
        for (int i = 0; i < 64; ++i) {
            vr[i] = __expf(vr[i] - mr); sr += vr[i];
            vw[i] = __expf(vw[i] - mw); sw += vw[i];
        }
#pragma unroll
        for (int o = 1; o < 16; o <<= 1) {
            sr += __shfl_xor(sr, o, 64);
            sw += __shfl_xor(sw, o, 64);
        }
        const float isr = 1.f / sr, isw = 1.f / sw;
        float ss = 0.f;
#pragma unroll
        for (int q = 0; q < 8; ++q) {
            float a8[8], r8[8];
#pragma unroll
            for (int i = 0; i < 8; ++i) {
                float a = vr[8 * q + i] * isr;
                float r2 = a * (vw[8 * q + i] * isw);
                a8[i] = a; r8[i] = r2;
                ss += r2;
            }
            if ((q >> 2) == kh) {
                int cb = (q - 4 * kh) * 128 + c16 * 8;
                *(uint4*)(&rwS[row * SLDW + cb])  = pack8(a8);
                *(uint4*)(&rw2S[row * SLDW + cb]) = pack8(r8);
            }
        }
#pragma unroll
        for (int o = 1; o < 16; o <<= 1) ss += __shfl_xor(ss, o, 64);
        if (c16 == 0) s_sh[row] = ss;
    }
    __syncthreads();

    f32x4 acc1 = {}, acc2 = {};
    for (int kt = 0; kt < 4; ++kt) {
#pragma unroll
        for (int i = 0; i < 4; ++i) {
            int idx = i * 256 + tid, r = idx >> 4, c = (idx & 15) * 8;
            *(uint4*)(&BsP[r * LDW + c]) = *(const uint4*)(memt + r * 1024 + k0 + kt * 128 + c);
        }
        __syncthreads();
#pragma unroll
        for (int kk = 0; kk < 128; kk += 32) {
            bf16x8 a1 = *(const bf16x8*)(&rwS[lrow * SLDW + kt * 128 + kk + 8 * lq]);
            bf16x8 a2 = *(const bf16x8*)(&rw2S[lrow * SLDW + kt * 128 + kk + 8 * lq]);
            bf16x8 b  = *(const bf16x8*)(&BsP[(16 * w + lrow) * LDW + kk + 8 * lq]);
            acc1 = MFMA_BF16(a1, b, acc1);
            acc2 = MFMA_BF16(a2, b, acc2);
        }
        __syncthreads();
    }

#pragma unroll
    for (int r = 0; r < 4; ++r) {
        int row_l = 4 * lq + r, col = 16 * w + lrow;
        int row_g = m0 + row_l;
        float p = acc1[r] - erase[row_g * 64 + col] * acc2[r];
        if (kh == 0) p += add[row_g * 64 + col] * s_sh[row_l];
        Ps[row_l * 72 + col] = f2bf(p);
    }
#pragma unroll
    for (int i = 0; i < 2; ++i) {
        int idx = i * 256 + tid, r = idx >> 3, c = (idx & 7) * 8;
        *(uint4*)(&BsP[r * LDW + c]) = *(const uint4*)(Wo_rn + r * 64 + c);
    }
    __syncthreads();

    f32x4 acc3 = {};
#pragma unroll
    for (int kk = 0; kk < 64; kk += 32) {
        bf16x8 a = *(const bf16x8*)(&Ps[lrow * 72 + kk + 8 * lq]);
        bf16x8 b = *(const bf16x8*)(&BsP[(16 * w + lrow) * LDW + kk + 8 * lq]);
        acc3 = MFMA_BF16(a, b, acc3);
    }
#pragma unroll
    for (int r = 0; r < 4; ++r) {
        int row_g = m0 + 4 * lq + r, col = 16 * w + lrow;
        atomicAdd(&out[row_g * 64 + col], acc3[r]);
    }
}

extern "C" void kernel_launch(void* const* d_in, const int* in_sizes, int n_in,
                              void* d_out, int out_size, void* d_ws, size_t ws_size,
                              hipStream_t stream)
{
    const float* x        = (const float*)d_in[0];
    const float* h_prev   = (const float*)d_in[1];
    const float* c_prev   = (const float*)d_in[2];
    const float* rwp      = (const float*)d_in[3];
    const float* memory   = (const float*)d_in[4];
    const float* W_ih     = (const float*)d_in[5];
    const float* b_ih     = (const float*)d_in[6];
    const float* W_hh     = (const float*)d_in[7];
    const float* b_hh     = (const float*)d_in[8];
    const float* W_read   = (const float*)d_in[9];
    const float* b_read   = (const float*)d_in[10];
    const float* W_write  = (const float*)d_in[11];
    const float* b_write  = (const float*)d_in[12];
    const float* W_erase  = (const float*)d_in[13];
    const float* b_erase  = (const float*)d_in[14];
    const float* W_add    = (const float*)d_in[15];
    const float* b_add    = (const float*)d_in[16];
    const float* W_out    = (const float*)d_in[17];
    const float* b_out    = (const float*)d_in[18];
    float* out = (float*)d_out;

    char* wsp = (char*)d_ws;
    u16*   x_t     = (u16*)(wsp + 0);           // 16 x 8oct x 128row x 8  (256 KB)
    u16*   ht_t    = (u16*)(wsp + 262144);      // 16 x 64oct x 128row x 8 (2 MB)
    u16*   wcat_t  = (u16*)(wsp + 2359296);     // 32bn x 5kt x 16oct x 64row x 8
    u16*   memt    = (u16*)(wsp + 4980736);     // 64 x 1024 bf16 memory^T
    u16*   Wcat2_t = (u16*)(wsp + 5111808);     // 35bn x 4kt x 16oct x 64row x 8
    u16*   Wo_rn   = (u16*)(wsp + 7405568);     // 64x64 bf16
    u16*   rpt     = (u16*)(wsp + 7413760);     // 16mt x 8oct x 128row x 8 bf16 (256 KB)
    u16*   hrn_t   = (u16*)(wsp + 9510912);     // 16 x 64oct x 128row x 8 (2 MB)
    u16*   pre_r   = (u16*)(wsp + 11608064);    // 2048x1024 bf16
    u16*   pre_w   = (u16*)(wsp + 15802368);    // 2048x1024 bf16
    float* erase   = (float*)(wsp + 19996672);  // 2048x64 fp32
    float* add     = (float*)(wsp + 20520960);  // 2048x64 fp32

    k_pre<<<640, 256, 0, stream>>>(x, h_prev, rwp, memory, W_ih, W_hh, W_read, W_write,
                                   W_erase, W_add, W_out,
                                   x_t, ht_t, wcat_t, Wcat2_t, Wo_rn, memt, rpt);
    k_gates<<<dim3(16, 32), 256, 0, stream>>>(rpt, x_t, ht_t, wcat_t, b_ih, b_hh, c_prev, hrn_t);
    k_heads<<<dim3(16, 35), 256, 0, stream>>>(hrn_t, Wcat2_t, b_read, b_write, b_erase, b_add, b_out,
                                              pre_r, pre_w, erase, add, out);
    k_tail<<<256, 256, 0, stream>>>(pre_r, pre_w, memt, Wo_rn, erase, add, out);
}